// Round 5
// baseline (194.495 us; speedup 1.0000x reference)
//
#include <hip/hip_runtime.h>
#include <cstdint>
#include <cstddef>

// Problem constants: W is [COUT, CIN]; x is [4*4096, CIN]. All I/O fp32.
#define CIN  1024
#define COUT 1024

typedef __attribute__((ext_vector_type(8))) short bf16x8;
typedef __attribute__((ext_vector_type(4))) float f32x4;

// ---------- fp32 -> bf16 (round-to-nearest-even) ----------
__device__ __forceinline__ unsigned short f2bf(float f) {
    union { float f; unsigned int i; } v;
    v.f = f;
    unsigned int u = v.i;
    u += 0x7FFFu + ((u >> 16) & 1u);
    return (unsigned short)(u >> 16);
}

// ---------- kernel 1: zero the fp32 W accumulation buffer ----------
__global__ void zero_f32(float4* __restrict__ p) {
    p[blockIdx.x * 256 + threadIdx.x] = float4{0.f, 0.f, 0.f, 0.f};
}

// ---------- kernel 2: scatter-add fp32 COO values into dense fp32 W ----------
__global__ void scatter_add(const float* __restrict__ vals,
                            const int* __restrict__ rows,
                            const int* __restrict__ cols,
                            float* __restrict__ W, int nnz) {
    int i = blockIdx.x * 256 + threadIdx.x;
    if (i < nnz) {
        atomicAdd(W + (size_t)rows[i] * CIN + cols[i], vals[i]);
    }
}

// ---------- kernel 3: fp32 -> bf16 bulk convert (W and x) ----------
__global__ void cvt_bf16_bulk(const float* __restrict__ src, unsigned short* __restrict__ dst) {
    size_t i = ((size_t)blockIdx.x * 256 + threadIdx.x) * 8;
    float4 v0 = *(const float4*)(src + i);
    float4 v1 = *(const float4*)(src + i + 4);
    union { bf16x8 v; unsigned short u[8]; } w;
    w.u[0] = f2bf(v0.x); w.u[1] = f2bf(v0.y); w.u[2] = f2bf(v0.z); w.u[3] = f2bf(v0.w);
    w.u[4] = f2bf(v1.x); w.u[5] = f2bf(v1.y); w.u[6] = f2bf(v1.z); w.u[7] = f2bf(v1.w);
    *(bf16x8*)(dst + i) = w.v;
}

// ---------- kernel 4: restructured GEMM — A direct-from-global, B chunk-staged ----------
// C[M,N] = A[M,K](bf16) * B[N,K](bf16)^T -> fp32. Block tile 128x128, 4 waves
// (2x2), each wave 64x64 via 4x4 tiles of mfma_f32_16x16x32_bf16.
//
// Structure change vs round 4 (the m97 plateau): B is staged in K-quarters of
// 256 (64 KB LDS, XOR-swizzled) -> only 4 vmcnt-drain barriers per block
// instead of 32. A fragments are loaded DIRECTLY global->VGPR (16 B/lane,
// naturally the MFMA A-layout); with no barrier between k0-subblocks the
// compiler can keep A loads in flight across MFMAs (fine-grained vmcnt),
// the AITER/flatmm-style overlap the 2-barrier loop couldn't express.
// Waves 0/1 (and 2/3) read identical A addresses -> L1 serves the twin.
__global__ __launch_bounds__(256) void gemm_adirect(
    const unsigned short* __restrict__ A,   // [M, K] bf16
    const unsigned short* __restrict__ B,   // [N, K] bf16
    float* __restrict__ C,                  // [M, N] fp32
    int M) {
    constexpr int K = CIN;
    constexpr int N = COUT;

    // B quarter: 128 rows x 256 k, row-major, 32 chunks of 16B per row,
    // chunk slot = (c & ~7) | ((c&7) ^ (row&7))  (same XOR family as round 4).
    __shared__ __align__(16) unsigned short Bs[128 * 256];

    const int tid   = threadIdx.x;
    const int lane  = tid & 63;
    const int wave  = tid >> 6;
    const int waveM = (wave >> 1) * 64;
    const int waveN = (wave & 1) * 64;
    const int quad  = lane >> 4;
    const int l16   = lane & 15;

    const int rowA0 = blockIdx.x * 128;
    const int rowB0 = blockIdx.y * 128;

    // --- B staging map (source-side swizzle) ---
    // iter i: thread t holds LDS elem off = i*2048 + t*8
    //   -> row r = i*8 + (t>>5), slot s = t&31; fetches chunk
    //      c = (s&~7) | ((s&7) ^ (t>>5))   (r&7 == t>>5 for all i).
    const int s_slot = tid & 31;
    const int r_low  = tid >> 5;            // 0..7
    const int c_data = (s_slot & ~7) | ((s_slot & 7) ^ r_low);
    const unsigned short* pb = B + (size_t)(rowB0 + r_low) * K + c_data * 8;
    const int ldsoff = tid * 8;             // wave-uniform base + lane*16B

    // --- A direct-load base: lane l16 owns row (waveM + t*16 + l16),
    //     quad owns k-subchunk quad*8 ---
    const unsigned short* pa = A + (size_t)(rowA0 + waveM + l16) * K + quad * 8;

    f32x4 acc[4][4] = {};
    const int s7 = l16 & 7;

    for (int kq = 0; kq < 4; ++kq) {
        if (kq) __syncthreads();            // LDS reuse guard (drains prev A loads too)
#pragma unroll
        for (int i = 0; i < 16; ++i) {
            __builtin_amdgcn_global_load_lds(
                (const __attribute__((address_space(1))) void*)(pb + kq * 256 + (size_t)i * 8 * K),
                (__attribute__((address_space(3))) void*)(Bs + i * 2048 + ldsoff),
                16, 0, 0);
        }
        __syncthreads();                    // B quarter visible

#pragma unroll
        for (int sub = 0; sub < 4; ++sub) {
            const int kbase = kq * 256 + sub * 64;   // global k of this subblock
#pragma unroll
            for (int ks = 0; ks < 2; ++ks) {
                bf16x8 af[4], bfr[4];
                const int cx = sub * 64 + ((ks * 4 + quad) ^ s7) * 8;  // swizzled LDS k-off
#pragma unroll
                for (int t = 0; t < 4; ++t) {
                    // A: direct global load, already in MFMA A-operand layout
                    af[t]  = *(const bf16x8*)(pa + (size_t)t * 16 * K + kbase + ks * 32);
                    // B: swizzled LDS read (conflict-free, 8-lane phases)
                    bfr[t] = *(const bf16x8*)(Bs + (waveN + t * 16 + l16) * 256 + cx);
                }
#pragma unroll
                for (int i = 0; i < 4; ++i)
#pragma unroll
                    for (int j = 0; j < 4; ++j)
                        acc[i][j] = __builtin_amdgcn_mfma_f32_16x16x32_bf16(
                            af[i], bfr[j], acc[i][j], 0, 0, 0);
            }
        }
    }

    // Epilogue: C/D layout col = lane&15, row = quad*4 + r (m89-verified).
#pragma unroll
    for (int i = 0; i < 4; ++i) {
#pragma unroll
        for (int r = 0; r < 4; ++r) {
            const int row = rowA0 + waveM + i * 16 + quad * 4 + r;
            float* cp = C + (size_t)row * N + rowB0 + waveN + l16;
#pragma unroll
            for (int j = 0; j < 4; ++j)
                cp[j * 16] = acc[i][j][r];
        }
    }
}

extern "C" void kernel_launch(void* const* d_in, const int* in_sizes, int n_in,
                              void* d_out, int out_size, void* d_ws, size_t ws_size,
                              hipStream_t stream) {
    const float* x    = (const float*)d_in[0];   // [M, CIN] fp32
    const float* vals = (const float*)d_in[1];   // [nnz] fp32
    const int*   idx  = (const int*)d_in[2];     // [2, nnz] int32

    float* out = (float*)d_out;                  // [M, COUT] fp32

    const int nnz = in_sizes[2] / 2;
    const int M   = in_sizes[0] / CIN;

    const size_t wf_bytes = (size_t)COUT * CIN * sizeof(float);          // 4 MB
    const size_t wb_bytes = (size_t)COUT * CIN * sizeof(unsigned short); // 2 MB

    float*          Wf = (float*)d_ws;
    unsigned short* Wb = (unsigned short*)((char*)d_ws + wf_bytes);
    unsigned short* Xb = (unsigned short*)((char*)d_ws + wf_bytes + wb_bytes);

    // 1) zero fp32 W (ws is poisoned 0xAA before every call)
    zero_f32<<<dim3(COUT * CIN / (256 * 4)), dim3(256), 0, stream>>>((float4*)Wf);
    // 2) scatter-add duplicates like coalesce()
    scatter_add<<<dim3((nnz + 255) / 256), dim3(256), 0, stream>>>(vals, idx, idx + nnz, Wf, nnz);
    // 3) W -> bf16
    cvt_bf16_bulk<<<dim3(COUT * CIN / (256 * 8)), dim3(256), 0, stream>>>(Wf, Wb);
    // 4) x -> bf16
    cvt_bf16_bulk<<<dim3((unsigned)((size_t)M * CIN / (256 * 8))), dim3(256), 0, stream>>>(x, Xb);
    // 5) restructured GEMM: out = x @ W^T
    gemm_adirect<<<dim3(M / 128, COUT / 128), dim3(256), 0, stream>>>(Xb, Wb, out, M);
}

// Round 6
// 177.217 us; speedup vs baseline: 1.0975x; 1.0975x over previous
//
#include <hip/hip_runtime.h>
#include <cstdint>
#include <cstddef>

// Problem constants: W is [COUT, CIN]; x is [4*4096, CIN]. All I/O fp32.
#define CIN  1024
#define COUT 1024

typedef __attribute__((ext_vector_type(8))) short bf16x8;
typedef __attribute__((ext_vector_type(4))) float f32x4;

// ---------- fp32 -> bf16 (round-to-nearest-even) ----------
__device__ __forceinline__ unsigned short f2bf(float f) {
    union { float f; unsigned int i; } v;
    v.f = f;
    unsigned int u = v.i;
    u += 0x7FFFu + ((u >> 16) & 1u);
    return (unsigned short)(u >> 16);
}

// Pack two fp32 -> bf16x2 in 2 adds + 1 v_perm (round-to-nearest, ties-away).
// Result = (hi16(b+0x8000) << 16) | hi16(a+0x8000).
__device__ __forceinline__ unsigned pk_bf2(float a, float b) {
    union { float f; unsigned u; } x, y;
    x.f = a; y.f = b;
    return __builtin_amdgcn_perm(y.u + 0x8000u, x.u + 0x8000u, 0x07060302u);
}

// ---------- kernel 1: zero the fp32 W accumulation buffer ----------
__global__ void zero_f32(float4* __restrict__ p) {
    p[blockIdx.x * 256 + threadIdx.x] = float4{0.f, 0.f, 0.f, 0.f};
}

// ---------- kernel 2: scatter-add fp32 COO values into dense fp32 W ----------
__global__ void scatter_add(const float* __restrict__ vals,
                            const int* __restrict__ rows,
                            const int* __restrict__ cols,
                            float* __restrict__ W, int nnz) {
    int i = blockIdx.x * 256 + threadIdx.x;
    if (i < nnz) {
        atomicAdd(W + (size_t)rows[i] * CIN + cols[i], vals[i]);
    }
}

// ---------- kernel 3: fp32 W -> bf16 W (RNE) ----------
__global__ void cvt_bf16_bulk(const float* __restrict__ src, unsigned short* __restrict__ dst) {
    size_t i = ((size_t)blockIdx.x * 256 + threadIdx.x) * 8;
    float4 v0 = *(const float4*)(src + i);
    float4 v1 = *(const float4*)(src + i + 4);
    union { bf16x8 v; unsigned short u[8]; } w;
    w.u[0] = f2bf(v0.x); w.u[1] = f2bf(v0.y); w.u[2] = f2bf(v0.z); w.u[3] = f2bf(v0.w);
    w.u[4] = f2bf(v1.x); w.u[5] = f2bf(v1.y); w.u[6] = f2bf(v1.z); w.u[7] = f2bf(v1.w);
    *(bf16x8*)(dst + i) = w.v;
}

// ---------- kernel 4: fused-cvt GEMM with XOR-swizzled LDS (round-4 structure) ----------
// C[M,N] = A[M,K](fp32, cvt to bf16 in-kernel) * B[N,K](bf16)^T -> fp32.
// 128x128x64 tile, 4 waves (2x2), 4x4 mfma_f32_16x16x32_bf16 per wave.
//
// LDS layout (per operand, [128 rows][8 chunks of 16B]): chunk slot for
// (row r, data-chunk c) is slot = c ^ (r&7).
//   - B staging: global_load_lds (dst = wave-base + lane*16B), swizzle applied
//     on the GLOBAL source side (round-4 scheme, conflict-free, coalesced).
//   - A staging: fp32 dwordx4 x2 -> add+v_perm pack -> ds_write_b128 at
//     tid*16B (consecutive threads -> consecutive 16B -> conflict-free).
//     Source chunk permuted identically, coalescing preserved (8 threads
//     cover one 256B fp32 row segment, permuted within it).
//   - Fragment reads: chunk ((ks*4+quad) ^ (l16&7)) -> each 8-lane phase is a
//     permutation of the 8 bank-quads -> 0 conflicts (verified round 4).
__global__ __launch_bounds__(256) void gemm_fused_cvt(
    const float* __restrict__ A,            // [M, K] fp32
    const unsigned short* __restrict__ B,   // [N, K] bf16
    float* __restrict__ C,                  // [M, N] fp32
    int M) {
    constexpr int K = CIN;
    constexpr int N = COUT;

    __shared__ __align__(16) unsigned short As[128 * 64];
    __shared__ __align__(16) unsigned short Bs[128 * 64];

    const int tid   = threadIdx.x;
    const int lane  = tid & 63;
    const int wave  = tid >> 6;
    const int waveM = (wave >> 1) * 64;
    const int waveN = (wave & 1) * 64;
    const int quad  = lane >> 4;
    const int l16   = lane & 15;

    const int rowA0 = blockIdx.x * 128;
    const int rowB0 = blockIdx.y * 128;

    // Staging map with source-side swizzle (round-4 scheme).
    const int stg_r  = tid >> 3;                 // 0..31 (row within 32-row group)
    const int c_slot = tid & 7;                  // LDS 16B-chunk slot in row
    const int c_data = c_slot ^ (stg_r & 7);     // data chunk to fetch
    const float*          pa = A + (size_t)(rowA0 + stg_r) * K + c_data * 8;
    const unsigned short* pb = B + (size_t)(rowB0 + stg_r) * K + c_data * 8;
    const int ldsoff = tid * 8;                  // elements (= lane*16B + wave base)

    f32x4 acc[4][4] = {};

    for (int k0 = 0; k0 < K; k0 += 64) {
        // B: async global->LDS (issue first; stays in flight over A work)
#pragma unroll
        for (int it = 0; it < 4; ++it) {
            __builtin_amdgcn_global_load_lds(
                (const __attribute__((address_space(1))) void*)(pb + k0 + (size_t)it * 32 * K),
                (__attribute__((address_space(3))) void*)(Bs + it * 2048 + ldsoff),
                16, 0, 0);
        }
        // A: fp32 load -> pack bf16 -> LDS (same swizzled slot as B scheme)
#pragma unroll
        for (int it = 0; it < 4; ++it) {
            const float* s = pa + k0 + (size_t)it * 32 * K;
            float4 v0 = *(const float4*)(s);
            float4 v1 = *(const float4*)(s + 4);
            union { bf16x8 v; unsigned u[4]; } w;
            w.u[0] = pk_bf2(v0.x, v0.y);
            w.u[1] = pk_bf2(v0.z, v0.w);
            w.u[2] = pk_bf2(v1.x, v1.y);
            w.u[3] = pk_bf2(v1.z, v1.w);
            *(bf16x8*)(As + it * 2048 + ldsoff) = w.v;
        }
        __syncthreads();   // drains vmcnt (glds + A loads) + lgkmcnt (ds_write)

        const int s7 = l16 & 7;
#pragma unroll
        for (int ks = 0; ks < 2; ++ks) {
            bf16x8 af[4], bfr[4];
            const int cx = ((ks * 4 + quad) ^ s7) * 8;   // swizzled k-chunk offset
#pragma unroll
            for (int t = 0; t < 4; ++t) {
                af[t]  = *(const bf16x8*)(As + (waveM + t * 16 + l16) * 64 + cx);
                bfr[t] = *(const bf16x8*)(Bs + (waveN + t * 16 + l16) * 64 + cx);
            }
#pragma unroll
            for (int i = 0; i < 4; ++i)
#pragma unroll
                for (int j = 0; j < 4; ++j)
                    acc[i][j] = __builtin_amdgcn_mfma_f32_16x16x32_bf16(
                        af[i], bfr[j], acc[i][j], 0, 0, 0);
        }
        __syncthreads();
    }

    // Epilogue: C/D layout col = lane&15, row = quad*4 + r (m89-verified).
#pragma unroll
    for (int i = 0; i < 4; ++i) {
#pragma unroll
        for (int r = 0; r < 4; ++r) {
            const int row = rowA0 + waveM + i * 16 + quad * 4 + r;
            float* cp = C + (size_t)row * N + rowB0 + waveN + l16;
#pragma unroll
            for (int j = 0; j < 4; ++j)
                cp[j * 16] = acc[i][j][r];
        }
    }
}

extern "C" void kernel_launch(void* const* d_in, const int* in_sizes, int n_in,
                              void* d_out, int out_size, void* d_ws, size_t ws_size,
                              hipStream_t stream) {
    const float* x    = (const float*)d_in[0];   // [M, CIN] fp32
    const float* vals = (const float*)d_in[1];   // [nnz] fp32
    const int*   idx  = (const int*)d_in[2];     // [2, nnz] int32

    float* out = (float*)d_out;                  // [M, COUT] fp32

    const int nnz = in_sizes[2] / 2;
    const int M   = in_sizes[0] / CIN;

    const size_t wf_bytes = (size_t)COUT * CIN * sizeof(float);          // 4 MB

    float*          Wf = (float*)d_ws;
    unsigned short* Wb = (unsigned short*)((char*)d_ws + wf_bytes);

    // 1) zero fp32 W (ws is poisoned 0xAA before every call)
    zero_f32<<<dim3(COUT * CIN / (256 * 4)), dim3(256), 0, stream>>>((float4*)Wf);
    // 2) scatter-add duplicates like coalesce()
    scatter_add<<<dim3((nnz + 255) / 256), dim3(256), 0, stream>>>(vals, idx, idx + nnz, Wf, nnz);
    // 3) W -> bf16
    cvt_bf16_bulk<<<dim3(COUT * CIN / (256 * 8)), dim3(256), 0, stream>>>(Wf, Wb);
    // 4) fused GEMM: out = x @ W^T (x converted to bf16 inside the kernel)
    gemm_fused_cvt<<<dim3(M / 128, COUT / 128), dim3(256), 0, stream>>>(x, Wb, out, M);
}